// Round 7
// baseline (339.103 us; speedup 1.0000x reference)
//
#include <hip/hip_runtime.h>
#include <hip/hip_bf16.h>

// GraphSAGE 2-layer, N=100K, E=1.6M, 128->128(relu)->64, log_softmax. fp32 in/out.
//
//   p = fp8(x@Wl1); q = bf16(x@Wr1 + b1)      (MFMA proj, operand-swapped)
//   h = bf16(relu(mean_nbr(p) + q))            (gather p fp8: 8 lanes/edge, idx-in-reg)
//   u = fp8(h@Wl2); v = bf16(h@Wr2 + b2)       (MFMA proj)
//   out = log_softmax(mean_nbr(u) + v)         (gather u fp8: 4 lanes/edge)
//
// r6 lesson: fusing CSR-build into the gather kills latency hiding (occupancy 66->29%,
// 2.35->1.55 TB/s). r7 reverts to the r5 skeleton (wave-per-node gather, 100K waves)
// and shortens the gather dependency chain: ONE coalesced index load per node into
// lane-distributed registers, then __shfl (ds_bpermute) supplies row addresses -- all
// row loads (uint4, 8 rows/instr) issue back-to-back with no index load in the chain.

typedef __attribute__((ext_vector_type(8))) short short8;   // 8 x bf16 = 4 VGPRs
typedef __attribute__((ext_vector_type(4))) float f32x4;
typedef __attribute__((ext_vector_type(2))) float f32x2;

#define NPB 512          // nodes per bucket (dst >> 9)
#define BCAP 16384       // edge capacity per bucket (mean 8163)
#define CHUNK 8192       // edges per bucket_scatter block

__device__ __forceinline__ ushort f2bf(float f) {           // round-to-nearest-even
    unsigned u = __float_as_uint(f);
    return (ushort)((u + 0x7fff + ((u >> 16) & 1)) >> 16);
}
__device__ __forceinline__ float bflo(unsigned v) { return __uint_as_float(v << 16); }
__device__ __forceinline__ float bfhi(unsigned v) { return __uint_as_float(v & 0xffff0000u); }
__device__ __forceinline__ unsigned pk4bf(float a, float b) {
    return (unsigned)f2bf(a) | ((unsigned)f2bf(b) << 16);
}
__device__ __forceinline__ f32x2 shflx2(f32x2 v, int m) {
    f32x2 r; r[0] = __shfl_xor(v[0], m); r[1] = __shfl_xor(v[1], m); return r;
}
// accumulate 16 fp8 (one uint4) into 8 f32x2
__device__ __forceinline__ void acc16(uint4 v, f32x2* a) {
    a[0] += __builtin_amdgcn_cvt_pk_f32_fp8((int)v.x, false);
    a[1] += __builtin_amdgcn_cvt_pk_f32_fp8((int)v.x, true);
    a[2] += __builtin_amdgcn_cvt_pk_f32_fp8((int)v.y, false);
    a[3] += __builtin_amdgcn_cvt_pk_f32_fp8((int)v.y, true);
    a[4] += __builtin_amdgcn_cvt_pk_f32_fp8((int)v.z, false);
    a[5] += __builtin_amdgcn_cvt_pk_f32_fp8((int)v.z, true);
    a[6] += __builtin_amdgcn_cvt_pk_f32_fp8((int)v.w, false);
    a[7] += __builtin_amdgcn_cvt_pk_f32_fp8((int)v.w, true);
}

// ---------- phase A: multi-split edges into node-range buckets (r5) ----------------
__global__ void bucket_scatter(const int* __restrict__ src, const int* __restrict__ dst,
                               int* __restrict__ bcount, unsigned* __restrict__ bbuf,
                               int E, int NB) {
    __shared__ unsigned entry[CHUNK];        // 32 KB: (src<<9)|(dst&511)
    __shared__ unsigned char ebkt[CHUNK];    // 8 KB: bucket id (dst>>9 < 256)
    __shared__ int lhist[256], lbase[256], lcur[256];
    int tid = threadIdx.x;
    lhist[tid] = 0;
    __syncthreads();
    int e0 = blockIdx.x * CHUNK;
    int cnt = min(CHUNK, E - e0);
    int nv = cnt >> 2;
    for (int t = tid; t < nv; t += 256) {
        int4 d4 = ((const int4*)(dst + e0))[t];
        int4 s4 = ((const int4*)(src + e0))[t];
        int i = t * 4;
        int b0 = d4.x >> 9, b1 = d4.y >> 9, b2 = d4.z >> 9, b3 = d4.w >> 9;
        entry[i + 0] = ((unsigned)s4.x << 9) | (unsigned)(d4.x & 511);
        entry[i + 1] = ((unsigned)s4.y << 9) | (unsigned)(d4.y & 511);
        entry[i + 2] = ((unsigned)s4.z << 9) | (unsigned)(d4.z & 511);
        entry[i + 3] = ((unsigned)s4.w << 9) | (unsigned)(d4.w & 511);
        ebkt[i + 0] = (unsigned char)b0; ebkt[i + 1] = (unsigned char)b1;
        ebkt[i + 2] = (unsigned char)b2; ebkt[i + 3] = (unsigned char)b3;
        atomicAdd(&lhist[b0], 1); atomicAdd(&lhist[b1], 1);
        atomicAdd(&lhist[b2], 1); atomicAdd(&lhist[b3], 1);
    }
    for (int i = (nv << 2) + tid; i < cnt; i += 256) {
        int d = dst[e0 + i], s = src[e0 + i];
        int b = d >> 9;
        entry[i] = ((unsigned)s << 9) | (unsigned)(d & 511);
        ebkt[i] = (unsigned char)b;
        atomicAdd(&lhist[b], 1);
    }
    __syncthreads();
    int h = lhist[tid];
    lbase[tid] = (h > 0) ? atomicAdd(&bcount[tid], h) : 0;
    lcur[tid] = 0;
    __syncthreads();
    for (int i = tid; i < cnt; i += 256) {
        int b = ebkt[i];
        int o = atomicAdd(&lcur[b], 1);
        bbuf[(long)b * BCAP + lbase[b] + o] = entry[i];
    }
}

// ---------- phase B: scan (block 0) fused with weight repack (blocks 1..) ----------
// Wf idx = ((ct*16 + kc)*16 + m)*8 + j holds W[k=kc*8+j][c=ct*16+m]
__device__ __forceinline__ void wfrag_one(const float* W, ushort* Wf, int i, int COLS) {
    int j = i & 7, m = (i >> 3) & 15, kc = (i >> 7) & 15, ct = i >> 11;
    Wf[i] = f2bf(W[(kc * 8 + j) * COLS + ct * 16 + m]);
}
__global__ void scan_cvtw_kernel(const int* __restrict__ bcount, int* __restrict__ bbase,
                                 int NB,
                                 const float* __restrict__ Wl1, const float* __restrict__ Wr1,
                                 const float* __restrict__ Wl2, const float* __restrict__ Wr2,
                                 ushort* __restrict__ Wf_l1, ushort* __restrict__ Wf_r1,
                                 ushort* __restrict__ Wf_l2, ushort* __restrict__ Wf_r2) {
    int tid = threadIdx.x;
    if (blockIdx.x == 0) {
        __shared__ int s[256];
        int v = (tid < NB) ? bcount[tid] : 0;
        s[tid] = v;
        __syncthreads();
        for (int off = 1; off < 256; off <<= 1) {
            int a = (tid >= off) ? s[tid - off] : 0;
            __syncthreads();
            s[tid] += a;
            __syncthreads();
        }
        if (tid < NB) bbase[tid] = s[tid] - v;
        return;
    }
    int i = (int)(blockIdx.x - 1) * 256 + tid;   // 49152 total
    if (i < 16384)       wfrag_one(Wl1, Wf_l1, i, 128);
    else if (i < 32768)  wfrag_one(Wr1, Wf_r1, i - 16384, 128);
    else if (i < 40960)  wfrag_one(Wl2, Wf_l2, i - 32768, 64);
    else if (i < 49152)  wfrag_one(Wr2, Wf_r2, i - 40960, 64);
}

// ---------- phase C: per-bucket degree count + scan + ordered placement (r5) -------
__global__ void build_csr(const unsigned* __restrict__ bbuf, const int* __restrict__ bcount,
                          const int* __restrict__ bbase, int* __restrict__ row_start,
                          int* __restrict__ degw, float* __restrict__ inv_deg,
                          int* __restrict__ ssrc, int N) {
    __shared__ int sdeg[NPB], lcur[NPB];
    int b = blockIdx.x, tid = threadIdx.x;
    int node0 = b * NPB;
    sdeg[tid] = 0; sdeg[tid + 256] = 0;
    __syncthreads();
    int cnt = bcount[b];
    long base = (long)b * BCAP;
    for (int i = tid; i < cnt; i += 256)
        atomicAdd(&sdeg[bbuf[base + i] & 511], 1);
    __syncthreads();
    int c0 = sdeg[tid], c1 = sdeg[tid + 256];
    for (int off = 1; off < NPB; off <<= 1) {   // inclusive Hillis-Steele over 512
        int a0 = (tid >= off) ? sdeg[tid - off] : 0;
        int a1 = (tid + 256 >= off) ? sdeg[tid + 256 - off] : 0;
        __syncthreads();
        sdeg[tid] += a0; sdeg[tid + 256] += a1;
        __syncthreads();
    }
    int bb = bbase[b];
    int rs0 = bb + sdeg[tid] - c0;
    int rs1 = bb + sdeg[tid + 256] - c1;
    lcur[tid] = rs0; lcur[tid + 256] = rs1;
    if (node0 + tid < N) {
        row_start[node0 + tid] = rs0;
        degw[node0 + tid] = c0;
        inv_deg[node0 + tid] = 1.0f / (float)(c0 > 1 ? c0 : 1);
    }
    if (node0 + tid + 256 < N) {
        row_start[node0 + tid + 256] = rs1;
        degw[node0 + tid + 256] = c1;
        inv_deg[node0 + tid + 256] = 1.0f / (float)(c1 > 1 ? c1 : 1);
    }
    __syncthreads();
    for (int i = tid; i < cnt; i += 256) {
        unsigned w = bbuf[base + i];
        int pos = atomicAdd(&lcur[w & 511], 1);
        ssrc[pos] = (int)(w >> 9);
    }
}

// ---------- dual projection: p = fp8(X@Wl), q = bf16(X@Wr + b) ---------------------
// Operand-swapped MFMA: D = Wfrag(A) * Xfrag(B) => lane holds 4 consecutive output
// cols of one node per ct => p packs to one dword (4xfp8), q to 8B (4xbf16).
template <int COLS, bool F32IN>
__device__ __forceinline__ void proj_body(int bid, int tid,
                            const void* __restrict__ xin,
                            const ushort* __restrict__ Wfl, const ushort* __restrict__ Wfr,
                            const float* __restrict__ bias,
                            unsigned char* __restrict__ p8, ushort* __restrict__ q, int N) {
    constexpr int CT = COLS / 16;
    int wave = tid >> 6, lane = tid & 63;
    int quad = lane >> 4, m = lane & 15;
    long row0 = (long)bid * 64 + wave * 16;
    long node = row0 + m;
    long arow = (node < N) ? node : (N - 1);

    f32x4 accp[CT], accq[CT];
#pragma unroll
    for (int ct = 0; ct < CT; ++ct) { accp[ct] = (f32x4)0.0f; accq[ct] = (f32x4)0.0f; }

#pragma unroll
    for (int kk = 0; kk < 128; kk += 32) {
        short8 b;                            // B-frag: B[k][n=lane&15] = x[node][k]
        if (F32IN) {
            const float* xf = (const float*)xin + arow * 128 + kk + quad * 8;
            float4 f0 = *(const float4*)xf;
            float4 f1 = *(const float4*)(xf + 4);
            b[0] = (short)f2bf(f0.x); b[1] = (short)f2bf(f0.y);
            b[2] = (short)f2bf(f0.z); b[3] = (short)f2bf(f0.w);
            b[4] = (short)f2bf(f1.x); b[5] = (short)f2bf(f1.y);
            b[6] = (short)f2bf(f1.z); b[7] = (short)f2bf(f1.w);
        } else {
            b = *(const short8*)((const ushort*)xin + arow * 128 + kk + quad * 8);
        }
        int kc = (kk >> 3) + quad;
#pragma unroll
        for (int ct = 0; ct < CT; ++ct) {
            long boff = (((long)(ct * 16 + kc) * 16) + m) * 8;
            short8 al = *(const short8*)(Wfl + boff);   // A-frag (weights)
            short8 ar = *(const short8*)(Wfr + boff);
            accp[ct] = __builtin_amdgcn_mfma_f32_16x16x32_bf16(al, b, accp[ct], 0, 0, 0);
            accq[ct] = __builtin_amdgcn_mfma_f32_16x16x32_bf16(ar, b, accq[ct], 0, 0, 0);
        }
    }

    if (node < N) {
#pragma unroll
        for (int ct = 0; ct < CT; ++ct) {
            int c0 = ct * 16 + quad * 4;
            float4 bv = *(const float4*)(bias + c0);
            float q0 = accq[ct][0] + bv.x, q1 = accq[ct][1] + bv.y;
            float q2 = accq[ct][2] + bv.z, q3 = accq[ct][3] + bv.w;
            unsigned w = (unsigned)__builtin_amdgcn_cvt_pk_fp8_f32(accp[ct][0], accp[ct][1], 0, false);
            w = (unsigned)__builtin_amdgcn_cvt_pk_fp8_f32(accp[ct][2], accp[ct][3], (int)w, true);
            *(unsigned*)(p8 + node * COLS + c0) = w;
            uint2 qw; qw.x = pk4bf(q0, q1); qw.y = pk4bf(q2, q3);
            *(uint2*)(q + node * COLS + c0) = qw;
        }
    }
}

__global__ void __launch_bounds__(256)
proj1_kernel(const float* __restrict__ x,
             const ushort* __restrict__ Wfl, const ushort* __restrict__ Wfr,
             const float* __restrict__ bias,
             unsigned char* __restrict__ p8, ushort* __restrict__ q, int N) {
    proj_body<128, true>((int)blockIdx.x, (int)threadIdx.x, x, Wfl, Wfr, bias, p8, q, N);
}
__global__ void __launch_bounds__(256)
proj2_kernel(const ushort* __restrict__ hb,
             const ushort* __restrict__ Wfl, const ushort* __restrict__ Wfr,
             const float* __restrict__ bias,
             unsigned char* __restrict__ u8, ushort* __restrict__ v, int N) {
    proj_body<64, false>((int)blockIdx.x, (int)threadIdx.x, hb, Wfl, Wfr, bias, u8, v, N);
}

// ---------- layer-1 aggregate: h = bf16(relu(mean_nbr(p) + q)) ---------------------
// Wave per node. One coalesced idx load (<=64 nbrs) into lane registers; __shfl
// supplies addresses; 8 lanes/edge x uint4 => 8 rows per instruction, all independent.
__global__ void __launch_bounds__(256)
agg_relu_kernel(const unsigned char* __restrict__ p8,  // N x 128 fp8
                const ushort* __restrict__ q,          // N x 128 bf16
                const int* __restrict__ ssrc,
                const int* __restrict__ row_start,
                const int* __restrict__ deg,
                const float* __restrict__ inv_deg,
                ushort* __restrict__ hb, int N) {
    int wave = threadIdx.x >> 6, lane = threadIdx.x & 63;
    int n = blockIdx.x * 4 + wave;
    if (n >= N) return;
    int g = lane >> 3, lm = lane & 7;              // 8 groups; cols lm*16..lm*16+15
    int start = row_start[n], d = deg[n];
    const int* sp = ssrc + start;
    const unsigned char* pb = p8 + lm * 16;
    f32x2 a[8] = {};
    for (int w = 0; w < d; w += 64) {              // one window covers deg<=64 (typ.)
        int rem = d - w;
        int li = lane < rem ? lane : rem - 1;
        int idxv = sp[w + li];                     // coalesced, lane-distributed
        int iters = rem < 64 ? rem : 64;
        for (int e0 = 0; e0 < iters; e0 += 16) {   // 2 row-load instrs in flight
            int eA = e0 + g, eB = e0 + 8 + g;
            int sA = __shfl(idxv, eA < iters ? eA : 0);
            int sB = __shfl(idxv, eB < iters ? eB : 0);
            uint4 vA = *(const uint4*)(pb + (long)sA * 128);
            uint4 vB = *(const uint4*)(pb + (long)sB * 128);
            if (eA >= iters) vA = make_uint4(0, 0, 0, 0);   // fp8 0x00 == 0.0
            if (eB >= iters) vB = make_uint4(0, 0, 0, 0);
            acc16(vA, a);
            acc16(vB, a);
        }
    }
#pragma unroll
    for (int t = 0; t < 8; ++t) {                  // merge the 8 edge slots
        a[t] += shflx2(a[t], 8);
        a[t] += shflx2(a[t], 16);
        a[t] += shflx2(a[t], 32);
    }
    if (g == 0) {                                  // lanes 0..7 store 16 cols each
        float iv = inv_deg[n];
        const uint4* qp = (const uint4*)(q + (long)n * 128 + lm * 16);
        uint4 qa = qp[0], qb = qp[1];
        unsigned qd[8] = {qa.x, qa.y, qa.z, qa.w, qb.x, qb.y, qb.z, qb.w};
        float hv[16];
#pragma unroll
        for (int j = 0; j < 16; ++j) hv[j] = a[j >> 1][j & 1] * iv;
#pragma unroll
        for (int j = 0; j < 8; ++j) {
            hv[2 * j]     = fmaxf(hv[2 * j] + bflo(qd[j]), 0.f);
            hv[2 * j + 1] = fmaxf(hv[2 * j + 1] + bfhi(qd[j]), 0.f);
        }
        uint4 ha, hbv;
        ha.x = pk4bf(hv[0], hv[1]);   ha.y = pk4bf(hv[2], hv[3]);
        ha.z = pk4bf(hv[4], hv[5]);   ha.w = pk4bf(hv[6], hv[7]);
        hbv.x = pk4bf(hv[8], hv[9]);  hbv.y = pk4bf(hv[10], hv[11]);
        hbv.z = pk4bf(hv[12], hv[13]); hbv.w = pk4bf(hv[14], hv[15]);
        uint4* hp = (uint4*)(hb + (long)n * 128 + lm * 16);
        hp[0] = ha; hp[1] = hbv;
    }
}

// ---------- layer-2 aggregate + log_softmax ----------------------------------------
// Wave per node; 4 lanes/edge x uint4 => 16 rows per instruction.
__global__ void __launch_bounds__(256)
agg_lsm_kernel(const unsigned char* __restrict__ u8,   // N x 64 fp8
               const ushort* __restrict__ vt,          // N x 64 bf16
               const int* __restrict__ ssrc,
               const int* __restrict__ row_start,
               const int* __restrict__ deg,
               const float* __restrict__ inv_deg,
               float* __restrict__ out, int N) {
    int wave = threadIdx.x >> 6, lane = threadIdx.x & 63;
    int n = blockIdx.x * 4 + wave;
    if (n >= N) return;
    int g = lane >> 2, lm = lane & 3;              // 16 groups; cols lm*16..lm*16+15
    int start = row_start[n], d = deg[n];
    const int* sp = ssrc + start;
    const unsigned char* ub = u8 + lm * 16;
    f32x2 a[8] = {};
    for (int w = 0; w < d; w += 64) {
        int rem = d - w;
        int li = lane < rem ? lane : rem - 1;
        int idxv = sp[w + li];
        int iters = rem < 64 ? rem : 64;
        for (int e0 = 0; e0 < iters; e0 += 32) {   // 2 row-load instrs in flight
            int eA = e0 + g, eB = e0 + 16 + g;
            int sA = __shfl(idxv, eA < iters ? eA : 0);
            int sB = __shfl(idxv, eB < iters ? eB : 0);
            uint4 vA = *(const uint4*)(ub + (long)sA * 64);
            uint4 vB = *(const uint4*)(ub + (long)sB * 64);
            if (eA >= iters) vA = make_uint4(0, 0, 0, 0);
            if (eB >= iters) vB = make_uint4(0, 0, 0, 0);
            acc16(vA, a);
            acc16(vB, a);
        }
    }
#pragma unroll
    for (int t = 0; t < 8; ++t) {                  // merge the 16 edge slots
        a[t] += shflx2(a[t], 4);
        a[t] += shflx2(a[t], 8);
        a[t] += shflx2(a[t], 16);
        a[t] += shflx2(a[t], 32);
    }
    float iv = inv_deg[n];
    const uint4* vp = (const uint4*)(vt + (long)n * 64 + lm * 16);
    uint4 va = vp[0], vb = vp[1];
    unsigned vd[8] = {va.x, va.y, va.z, va.w, vb.x, vb.y, vb.z, vb.w};
    float z[16];
#pragma unroll
    for (int j = 0; j < 8; ++j) {
        z[2 * j]     = a[j][0] * iv + bflo(vd[j]);
        z[2 * j + 1] = a[j][1] * iv + bfhi(vd[j]);
    }
    float mx = z[0];
#pragma unroll
    for (int j = 1; j < 16; ++j) mx = fmaxf(mx, z[j]);
    mx = fmaxf(mx, __shfl_xor(mx, 1));
    mx = fmaxf(mx, __shfl_xor(mx, 2));             // full 64-col max (over lm bits)
    float es = 0.f;
#pragma unroll
    for (int j = 0; j < 16; ++j) es += __expf(z[j] - mx);
    es += __shfl_xor(es, 1);
    es += __shfl_xor(es, 2);
    float ls = mx + __logf(es);
    if (g == 0) {                                  // lanes 0..3 store 16 floats each
        float* op = out + (long)n * 64 + lm * 16;
#pragma unroll
        for (int j4 = 0; j4 < 4; ++j4) {
            float4 o4;
            o4.x = z[j4 * 4 + 0] - ls; o4.y = z[j4 * 4 + 1] - ls;
            o4.z = z[j4 * 4 + 2] - ls; o4.w = z[j4 * 4 + 3] - ls;
            *(float4*)(op + j4 * 4) = o4;
        }
    }
}

// -----------------------------------------------------------------------------------
extern "C" void kernel_launch(void* const* d_in, const int* in_sizes, int n_in,
                              void* d_out, int out_size, void* d_ws, size_t ws_size,
                              hipStream_t stream) {
    const float* x   = (const float*)d_in[0];
    const int*   ei  = (const int*)d_in[1];
    const float* Wl1 = (const float*)d_in[2];
    const float* Wr1 = (const float*)d_in[3];
    const float* b1  = (const float*)d_in[4];
    const float* Wl2 = (const float*)d_in[5];
    const float* Wr2 = (const float*)d_in[6];
    const float* b2  = (const float*)d_in[7];

    const int N = in_sizes[0] / 128;
    const int E = in_sizes[1] / 2;
    const int* src = ei;
    const int* dst = ei + E;
    const int NB = (N + NPB - 1) / NPB;             // 196 buckets for N=100000

    size_t off = 0;
    auto take = [&](size_t nbytes) -> void* {
        void* ptr = (void*)((char*)d_ws + off);
        off += (nbytes + 255) & ~(size_t)255;
        return ptr;
    };
    int*      bcount    = (int*)take((size_t)NB * 4);
    int*      bbase     = (int*)take((size_t)NB * 4);
    unsigned* bbuf      = (unsigned*)take((size_t)NB * BCAP * 4);   // 12.8 MB
    int*      row_start = (int*)take((size_t)N * 4);
    int*      degw      = (int*)take((size_t)N * 4);
    float*    inv_deg   = (float*)take((size_t)N * 4);
    int*      ssrc      = (int*)take((size_t)E * 4);
    unsigned char* p8   = (unsigned char*)take((size_t)N * 128);    // reused as u8
    ushort*   q         = (ushort*)take((size_t)N * 128 * 2);       // reused as v
    ushort*   hb        = (ushort*)take((size_t)N * 128 * 2);
    ushort*   Wf_l1     = (ushort*)take(128 * 128 * 2);
    ushort*   Wf_r1     = (ushort*)take(128 * 128 * 2);
    ushort*   Wf_l2     = (ushort*)take(64 * 128 * 2);
    ushort*   Wf_r2     = (ushort*)take(64 * 128 * 2);
    unsigned char* u8 = p8;   // p dead after agg_relu
    ushort*        v  = q;    // q dead after agg_relu
    (void)ws_size; (void)n_in; (void)out_size;

    hipMemsetAsync(bcount, 0, (size_t)NB * 4, stream);

    bucket_scatter<<<(E + CHUNK - 1) / CHUNK, 256, 0, stream>>>(src, dst, bcount, bbuf, E, NB);
    scan_cvtw_kernel<<<1 + 192, 256, 0, stream>>>(bcount, bbase, NB,
                                                  Wl1, Wr1, Wl2, Wr2,
                                                  Wf_l1, Wf_r1, Wf_l2, Wf_r2);
    build_csr<<<NB, 256, 0, stream>>>(bbuf, bcount, bbase, row_start, degw, inv_deg, ssrc, N);

    // layer 1
    proj1_kernel<<<(N + 63) / 64, 256, 0, stream>>>(x, Wf_l1, Wf_r1, b1, p8, q, N);
    agg_relu_kernel<<<(N + 3) / 4, 256, 0, stream>>>(p8, q, ssrc, row_start, degw, inv_deg, hb, N);

    // layer 2
    proj2_kernel<<<(N + 63) / 64, 256, 0, stream>>>(hb, Wf_l2, Wf_r2, b2, u8, v, N);
    agg_lsm_kernel<<<(N + 3) / 4, 256, 0, stream>>>(u8, v, ssrc, row_start, degw, inv_deg,
                                                    (float*)d_out, N);
}

// Round 8
// 285.726 us; speedup vs baseline: 1.1868x; 1.1868x over previous
//
#include <hip/hip_runtime.h>
#include <hip/hip_bf16.h>

// GraphSAGE 2-layer, N=100K, E=1.6M, 128->128(relu)->64, log_softmax. fp32 in/out.
//
//   p = fp8(x@Wl1); q = bf16(x@Wr1 + b1)      (MFMA proj, operand-swapped)
//   h = bf16(relu(mean_nbr(p) + q))            (r5 gather: 16 lanes/edge, 8B)
//   u = fp8(h@Wl2); v = bf16(h@Wr2 + b2)       (MFMA proj)
//   out = log_softmax(mean_nbr(u) + v)         (r5 gather: 8 lanes/edge, 8B)
//
// r7 lesson: >8 lanes/edge makes the per-node shfl-merge tail dominate at deg~16
// (agg_lsm 22->84us). r8 = r5's measured-best gather kernels verbatim + pipeline
// consolidation: bucket-LOCAL row_start (b*BCAP+local) kills the global scan; split
// grids overlap independent stages: K1 = scatter||cvt_w, K2 = build_csr||proj1
// (LDS/int pipe || MFMA/VMEM pipe). 8 dispatches -> 6.

typedef __attribute__((ext_vector_type(8))) short short8;   // 8 x bf16 = 4 VGPRs
typedef __attribute__((ext_vector_type(4))) float f32x4;
typedef __attribute__((ext_vector_type(2))) float f32x2;

#define NPB 512          // nodes per bucket (dst >> 9)
#define BCAP 16384       // edge capacity per bucket (mean 8163)
#define CHUNK 8192       // edges per bucket_scatter block

__device__ __forceinline__ ushort f2bf(float f) {           // round-to-nearest-even
    unsigned u = __float_as_uint(f);
    return (ushort)((u + 0x7fff + ((u >> 16) & 1)) >> 16);
}
__device__ __forceinline__ float bflo(unsigned v) { return __uint_as_float(v << 16); }
__device__ __forceinline__ float bfhi(unsigned v) { return __uint_as_float(v & 0xffff0000u); }
__device__ __forceinline__ unsigned pk4bf(float a, float b) {
    return (unsigned)f2bf(a) | ((unsigned)f2bf(b) << 16);
}
__device__ __forceinline__ f32x2 shflx2(f32x2 v, int m) {
    f32x2 r; r[0] = __shfl_xor(v[0], m); r[1] = __shfl_xor(v[1], m); return r;
}

// ---------- weight repack into MFMA fragment order ---------------------------------
// Wf idx = ((ct*16 + kc)*16 + m)*8 + j holds W[k=kc*8+j][c=ct*16+m]
__device__ __forceinline__ void wfrag_one(const float* W, ushort* Wf, int i, int COLS) {
    int j = i & 7, m = (i >> 3) & 15, kc = (i >> 7) & 15, ct = i >> 11;
    Wf[i] = f2bf(W[(kc * 8 + j) * COLS + ct * 16 + m]);
}

// ---------- K1: bucket_scatter (blocks 0..NSC) || cvt_w (rest) ---------------------
__global__ void __launch_bounds__(256)
k1_scatter_cvtw(const int* __restrict__ src, const int* __restrict__ dst,
                int* __restrict__ bcount, unsigned* __restrict__ bbuf, int E, int NSC,
                const float* __restrict__ Wl1, const float* __restrict__ Wr1,
                const float* __restrict__ Wl2, const float* __restrict__ Wr2,
                ushort* __restrict__ Wf_l1, ushort* __restrict__ Wf_r1,
                ushort* __restrict__ Wf_l2, ushort* __restrict__ Wf_r2) {
    int tid = threadIdx.x;
    if ((int)blockIdx.x >= NSC) {
        int i = ((int)blockIdx.x - NSC) * 256 + tid;   // 49152 total
        if (i < 16384)       wfrag_one(Wl1, Wf_l1, i, 128);
        else if (i < 32768)  wfrag_one(Wr1, Wf_r1, i - 16384, 128);
        else if (i < 40960)  wfrag_one(Wl2, Wf_l2, i - 32768, 64);
        else if (i < 49152)  wfrag_one(Wr2, Wf_r2, i - 40960, 64);
        return;
    }
    __shared__ unsigned entry[CHUNK];        // 32 KB: (src<<9)|(dst&511)
    __shared__ unsigned char ebkt[CHUNK];    // 8 KB: bucket id (dst>>9 < 256)
    __shared__ int lhist[256], lbase[256], lcur[256];
    lhist[tid] = 0;
    __syncthreads();
    int e0 = blockIdx.x * CHUNK;
    int cnt = min(CHUNK, E - e0);
    int nv = cnt >> 2;
    for (int t = tid; t < nv; t += 256) {
        int4 d4 = ((const int4*)(dst + e0))[t];
        int4 s4 = ((const int4*)(src + e0))[t];
        int i = t * 4;
        int b0 = d4.x >> 9, b1 = d4.y >> 9, b2 = d4.z >> 9, b3 = d4.w >> 9;
        entry[i + 0] = ((unsigned)s4.x << 9) | (unsigned)(d4.x & 511);
        entry[i + 1] = ((unsigned)s4.y << 9) | (unsigned)(d4.y & 511);
        entry[i + 2] = ((unsigned)s4.z << 9) | (unsigned)(d4.z & 511);
        entry[i + 3] = ((unsigned)s4.w << 9) | (unsigned)(d4.w & 511);
        ebkt[i + 0] = (unsigned char)b0; ebkt[i + 1] = (unsigned char)b1;
        ebkt[i + 2] = (unsigned char)b2; ebkt[i + 3] = (unsigned char)b3;
        atomicAdd(&lhist[b0], 1); atomicAdd(&lhist[b1], 1);
        atomicAdd(&lhist[b2], 1); atomicAdd(&lhist[b3], 1);
    }
    for (int i = (nv << 2) + tid; i < cnt; i += 256) {
        int d = dst[e0 + i], s = src[e0 + i];
        int b = d >> 9;
        entry[i] = ((unsigned)s << 9) | (unsigned)(d & 511);
        ebkt[i] = (unsigned char)b;
        atomicAdd(&lhist[b], 1);
    }
    __syncthreads();
    int h = lhist[tid];
    lbase[tid] = (h > 0) ? atomicAdd(&bcount[tid], h) : 0;
    lcur[tid] = 0;
    __syncthreads();
    for (int i = tid; i < cnt; i += 256) {
        int b = ebkt[i];
        int o = atomicAdd(&lcur[b], 1);
        bbuf[(long)b * BCAP + lbase[b] + o] = entry[i];
    }
}

// ---------- dual projection body: p = fp8(X@Wl), q = bf16(X@Wr + b) ----------------
// Operand-swapped MFMA: D = Wfrag(A) * Xfrag(B) => lane holds 4 consecutive output
// cols of one node per ct => p packs to one dword (4xfp8), q to 8B (4xbf16).
template <int COLS, bool F32IN>
__device__ __forceinline__ void proj_body(int bid, int tid,
                            const void* __restrict__ xin,
                            const ushort* __restrict__ Wfl, const ushort* __restrict__ Wfr,
                            const float* __restrict__ bias,
                            unsigned char* __restrict__ p8, ushort* __restrict__ q, int N) {
    constexpr int CT = COLS / 16;
    int wave = tid >> 6, lane = tid & 63;
    int quad = lane >> 4, m = lane & 15;
    long row0 = (long)bid * 64 + wave * 16;
    long node = row0 + m;
    long arow = (node < N) ? node : (N - 1);

    f32x4 accp[CT], accq[CT];
#pragma unroll
    for (int ct = 0; ct < CT; ++ct) { accp[ct] = (f32x4)0.0f; accq[ct] = (f32x4)0.0f; }

#pragma unroll
    for (int kk = 0; kk < 128; kk += 32) {
        short8 b;                            // B-frag: B[k][n=lane&15] = x[node][k]
        if (F32IN) {
            const float* xf = (const float*)xin + arow * 128 + kk + quad * 8;
            float4 f0 = *(const float4*)xf;
            float4 f1 = *(const float4*)(xf + 4);
            b[0] = (short)f2bf(f0.x); b[1] = (short)f2bf(f0.y);
            b[2] = (short)f2bf(f0.z); b[3] = (short)f2bf(f0.w);
            b[4] = (short)f2bf(f1.x); b[5] = (short)f2bf(f1.y);
            b[6] = (short)f2bf(f1.z); b[7] = (short)f2bf(f1.w);
        } else {
            b = *(const short8*)((const ushort*)xin + arow * 128 + kk + quad * 8);
        }
        int kc = (kk >> 3) + quad;
#pragma unroll
        for (int ct = 0; ct < CT; ++ct) {
            long boff = (((long)(ct * 16 + kc) * 16) + m) * 8;
            short8 al = *(const short8*)(Wfl + boff);   // A-frag (weights)
            short8 ar = *(const short8*)(Wfr + boff);
            accp[ct] = __builtin_amdgcn_mfma_f32_16x16x32_bf16(al, b, accp[ct], 0, 0, 0);
            accq[ct] = __builtin_amdgcn_mfma_f32_16x16x32_bf16(ar, b, accq[ct], 0, 0, 0);
        }
    }

    if (node < N) {
#pragma unroll
        for (int ct = 0; ct < CT; ++ct) {
            int c0 = ct * 16 + quad * 4;
            float4 bv = *(const float4*)(bias + c0);
            float q0 = accq[ct][0] + bv.x, q1 = accq[ct][1] + bv.y;
            float q2 = accq[ct][2] + bv.z, q3 = accq[ct][3] + bv.w;
            unsigned w = (unsigned)__builtin_amdgcn_cvt_pk_fp8_f32(accp[ct][0], accp[ct][1], 0, false);
            w = (unsigned)__builtin_amdgcn_cvt_pk_fp8_f32(accp[ct][2], accp[ct][3], (int)w, true);
            *(unsigned*)(p8 + node * COLS + c0) = w;
            uint2 qw; qw.x = pk4bf(q0, q1); qw.y = pk4bf(q2, q3);
            *(uint2*)(q + node * COLS + c0) = qw;
        }
    }
}

// ---------- K2: build_csr (blocks 0..NB, bucket-local row_start) || proj1 ----------
__global__ void __launch_bounds__(256)
k2_csr_proj1(const unsigned* __restrict__ bbuf, const int* __restrict__ bcount,
             int* __restrict__ row_start, int* __restrict__ degw,
             float* __restrict__ inv_deg, int* __restrict__ ssrc, int NBcsr, int N,
             const float* __restrict__ x,
             const ushort* __restrict__ Wfl, const ushort* __restrict__ Wfr,
             const float* __restrict__ bias,
             unsigned char* __restrict__ p8, ushort* __restrict__ q) {
    int tid = threadIdx.x;
    if ((int)blockIdx.x >= NBcsr) {
        proj_body<128, true>((int)blockIdx.x - NBcsr, tid, x, Wfl, Wfr, bias, p8, q, N);
        return;
    }
    __shared__ int sdeg[NPB], lcur[NPB];
    int b = blockIdx.x;
    int node0 = b * NPB;
    sdeg[tid] = 0; sdeg[tid + 256] = 0;
    __syncthreads();
    int cnt = bcount[b];
    long base = (long)b * BCAP;
    for (int i = tid; i < cnt; i += 256)
        atomicAdd(&sdeg[bbuf[base + i] & 511], 1);
    __syncthreads();
    int c0 = sdeg[tid], c1 = sdeg[tid + 256];
    for (int off = 1; off < NPB; off <<= 1) {   // inclusive Hillis-Steele over 512
        int a0 = (tid >= off) ? sdeg[tid - off] : 0;
        int a1 = (tid + 256 >= off) ? sdeg[tid + 256 - off] : 0;
        __syncthreads();
        sdeg[tid] += a0; sdeg[tid + 256] += a1;
        __syncthreads();
    }
    int rs0 = sdeg[tid] - c0;                   // bucket-local exclusive scan
    int rs1 = sdeg[tid + 256] - c1;
    lcur[tid] = rs0; lcur[tid + 256] = rs1;
    if (node0 + tid < N) {
        row_start[node0 + tid] = (int)(base + rs0);
        degw[node0 + tid] = c0;
        inv_deg[node0 + tid] = 1.0f / (float)(c0 > 1 ? c0 : 1);
    }
    if (node0 + tid + 256 < N) {
        row_start[node0 + tid + 256] = (int)(base + rs1);
        degw[node0 + tid + 256] = c1;
        inv_deg[node0 + tid + 256] = 1.0f / (float)(c1 > 1 ? c1 : 1);
    }
    __syncthreads();
    for (int i = tid; i < cnt; i += 256) {
        unsigned w = bbuf[base + i];
        int pos = atomicAdd(&lcur[w & 511], 1);
        ssrc[base + pos] = (int)(w >> 9);
    }
}

// ---------- layer-1 aggregate (r5 verbatim): h = bf16(relu(mean_nbr(p) + q)) -------
// One wave per node; 16 lanes per edge, 8B/lane: one instr = 4 rows (512B).
__global__ void __launch_bounds__(256)
agg_relu_kernel(const unsigned char* __restrict__ p8,  // N x 128 fp8
                const ushort* __restrict__ q,          // N x 128 bf16
                const int* __restrict__ ssrc,
                const int* __restrict__ row_start,
                const int* __restrict__ deg,
                const float* __restrict__ inv_deg,
                ushort* __restrict__ hb, int N) {
    int wave = threadIdx.x >> 6, lane = threadIdx.x & 63;
    int n = blockIdx.x * 4 + wave;
    if (n >= N) return;
    int g = lane >> 4, lm = lane & 15;             // edge slot / cols lm*8..lm*8+7
    int start = row_start[n], d = deg[n];
    const int* sp = ssrc + start;
    const unsigned char* pb = p8 + lm * 8;
    f32x2 a0 = (f32x2)0.f, a1 = (f32x2)0.f, a2 = (f32x2)0.f, a3 = (f32x2)0.f;
    int j = 0;
    for (; j + 16 <= d; j += 16) {                 // 4 row loads = 16 edges in flight
        int s0 = sp[j + g], s1 = sp[j + 4 + g], s2 = sp[j + 8 + g], s3 = sp[j + 12 + g];
        uint2 v0 = *(const uint2*)(pb + (long)s0 * 128);
        uint2 v1 = *(const uint2*)(pb + (long)s1 * 128);
        uint2 v2 = *(const uint2*)(pb + (long)s2 * 128);
        uint2 v3 = *(const uint2*)(pb + (long)s3 * 128);
#pragma unroll
        for (int t = 0; t < 4; ++t) {
            uint2 vv = (t == 0) ? v0 : (t == 1) ? v1 : (t == 2) ? v2 : v3;
            a0 += __builtin_amdgcn_cvt_pk_f32_fp8((int)vv.x, false);
            a1 += __builtin_amdgcn_cvt_pk_f32_fp8((int)vv.x, true);
            a2 += __builtin_amdgcn_cvt_pk_f32_fp8((int)vv.y, false);
            a3 += __builtin_amdgcn_cvt_pk_f32_fp8((int)vv.y, true);
        }
    }
    for (; j < d; j += 4) {                        // predicated tail, 4 edges/iter
        int idx = j + g;
        int s = sp[idx < d ? idx : j];
        uint2 vv = *(const uint2*)(pb + (long)s * 128);
        if (idx < d) {
            a0 += __builtin_amdgcn_cvt_pk_f32_fp8((int)vv.x, false);
            a1 += __builtin_amdgcn_cvt_pk_f32_fp8((int)vv.x, true);
            a2 += __builtin_amdgcn_cvt_pk_f32_fp8((int)vv.y, false);
            a3 += __builtin_amdgcn_cvt_pk_f32_fp8((int)vv.y, true);
        }
    }
    a0 += shflx2(a0, 16); a1 += shflx2(a1, 16);
    a2 += shflx2(a2, 16); a3 += shflx2(a3, 16);
    a0 += shflx2(a0, 32); a1 += shflx2(a1, 32);
    a2 += shflx2(a2, 32); a3 += shflx2(a3, 32);
    if (g == 0) {
        float iv = inv_deg[n];
        uint4 qv = *(const uint4*)(q + (long)n * 128 + lm * 8);
        float h0 = fmaxf(a0[0] * iv + bflo(qv.x), 0.f);
        float h1 = fmaxf(a0[1] * iv + bfhi(qv.x), 0.f);
        float h2 = fmaxf(a1[0] * iv + bflo(qv.y), 0.f);
        float h3 = fmaxf(a1[1] * iv + bfhi(qv.y), 0.f);
        float h4 = fmaxf(a2[0] * iv + bflo(qv.z), 0.f);
        float h5 = fmaxf(a2[1] * iv + bfhi(qv.z), 0.f);
        float h6 = fmaxf(a3[0] * iv + bflo(qv.w), 0.f);
        float h7 = fmaxf(a3[1] * iv + bfhi(qv.w), 0.f);
        uint4 hw;
        hw.x = pk4bf(h0, h1); hw.y = pk4bf(h2, h3);
        hw.z = pk4bf(h4, h5); hw.w = pk4bf(h6, h7);
        *(uint4*)(hb + (long)n * 128 + lm * 8) = hw;
    }
}

// ---------- proj2 (standalone) -----------------------------------------------------
__global__ void __launch_bounds__(256)
proj2_kernel(const ushort* __restrict__ hb,
             const ushort* __restrict__ Wfl, const ushort* __restrict__ Wfr,
             const float* __restrict__ bias,
             unsigned char* __restrict__ u8, ushort* __restrict__ v, int N) {
    proj_body<64, false>((int)blockIdx.x, (int)threadIdx.x, hb, Wfl, Wfr, bias, u8, v, N);
}

// ---------- layer-2 aggregate + log_softmax (r5 verbatim) --------------------------
// One wave per node; 8 lanes per edge, 8B/lane: one instr = 8 rows (512B).
__global__ void __launch_bounds__(256)
agg_lsm_kernel(const unsigned char* __restrict__ u8,   // N x 64 fp8
               const ushort* __restrict__ v,           // N x 64 bf16
               const int* __restrict__ ssrc,
               const int* __restrict__ row_start,
               const int* __restrict__ deg,
               const float* __restrict__ inv_deg,
               float* __restrict__ out, int N) {
    int wave = threadIdx.x >> 6, lane = threadIdx.x & 63;
    int n = blockIdx.x * 4 + wave;
    if (n >= N) return;
    int g = lane >> 3, lm = lane & 7;              // edge slot / cols lm*8..lm*8+7
    int start = row_start[n], d = deg[n];
    const int* sp = ssrc + start;
    const unsigned char* ub = u8 + lm * 8;
    f32x2 a0 = (f32x2)0.f, a1 = (f32x2)0.f, a2 = (f32x2)0.f, a3 = (f32x2)0.f;
    int j = 0;
    for (; j + 16 <= d; j += 16) {                 // 2 row loads = 16 edges in flight
        int s0 = sp[j + g], s1 = sp[j + 8 + g];
        uint2 v0 = *(const uint2*)(ub + (long)s0 * 64);
        uint2 v1 = *(const uint2*)(ub + (long)s1 * 64);
#pragma unroll
        for (int t = 0; t < 2; ++t) {
            uint2 vv = (t == 0) ? v0 : v1;
            a0 += __builtin_amdgcn_cvt_pk_f32_fp8((int)vv.x, false);
            a1 += __builtin_amdgcn_cvt_pk_f32_fp8((int)vv.x, true);
            a2 += __builtin_amdgcn_cvt_pk_f32_fp8((int)vv.y, false);
            a3 += __builtin_amdgcn_cvt_pk_f32_fp8((int)vv.y, true);
        }
    }
    for (; j < d; j += 8) {                        // predicated tail, 8 edges/iter
        int idx = j + g;
        int s = sp[idx < d ? idx : j];
        uint2 vv = *(const uint2*)(ub + (long)s * 64);
        if (idx < d) {
            a0 += __builtin_amdgcn_cvt_pk_f32_fp8((int)vv.x, false);
            a1 += __builtin_amdgcn_cvt_pk_f32_fp8((int)vv.x, true);
            a2 += __builtin_amdgcn_cvt_pk_f32_fp8((int)vv.y, false);
            a3 += __builtin_amdgcn_cvt_pk_f32_fp8((int)vv.y, true);
        }
    }
    a0 += shflx2(a0, 8);  a1 += shflx2(a1, 8);  a2 += shflx2(a2, 8);  a3 += shflx2(a3, 8);
    a0 += shflx2(a0, 16); a1 += shflx2(a1, 16); a2 += shflx2(a2, 16); a3 += shflx2(a3, 16);
    a0 += shflx2(a0, 32); a1 += shflx2(a1, 32); a2 += shflx2(a2, 32); a3 += shflx2(a3, 32);

    float iv = inv_deg[n];
    uint4 vv = *(const uint4*)(v + (long)n * 64 + lm * 8);
    float z0 = a0[0] * iv + bflo(vv.x), z1 = a0[1] * iv + bfhi(vv.x);
    float z2 = a1[0] * iv + bflo(vv.y), z3 = a1[1] * iv + bfhi(vv.y);
    float z4 = a2[0] * iv + bflo(vv.z), z5 = a2[1] * iv + bfhi(vv.z);
    float z6 = a3[0] * iv + bflo(vv.w), z7 = a3[1] * iv + bfhi(vv.w);
    float mx = fmaxf(fmaxf(fmaxf(z0, z1), fmaxf(z2, z3)),
                     fmaxf(fmaxf(z4, z5), fmaxf(z6, z7)));
#pragma unroll
    for (int o = 4; o > 0; o >>= 1) mx = fmaxf(mx, __shfl_xor(mx, o));   // over lm bits
    float e = (__expf(z0 - mx) + __expf(z1 - mx)) + (__expf(z2 - mx) + __expf(z3 - mx)) +
              (__expf(z4 - mx) + __expf(z5 - mx)) + (__expf(z6 - mx) + __expf(z7 - mx));
#pragma unroll
    for (int o = 4; o > 0; o >>= 1) e += __shfl_xor(e, o);
    float ls = mx + __logf(e);
    if (g == 0) {                                  // 8 lanes store 8 floats each
        float4 o0, o1;
        o0.x = z0 - ls; o0.y = z1 - ls; o0.z = z2 - ls; o0.w = z3 - ls;
        o1.x = z4 - ls; o1.y = z5 - ls; o1.z = z6 - ls; o1.w = z7 - ls;
        *(float4*)(out + (long)n * 64 + lm * 8) = o0;
        *(float4*)(out + (long)n * 64 + lm * 8 + 4) = o1;
    }
}

// -----------------------------------------------------------------------------------
extern "C" void kernel_launch(void* const* d_in, const int* in_sizes, int n_in,
                              void* d_out, int out_size, void* d_ws, size_t ws_size,
                              hipStream_t stream) {
    const float* x   = (const float*)d_in[0];
    const int*   ei  = (const int*)d_in[1];
    const float* Wl1 = (const float*)d_in[2];
    const float* Wr1 = (const float*)d_in[3];
    const float* b1  = (const float*)d_in[4];
    const float* Wl2 = (const float*)d_in[5];
    const float* Wr2 = (const float*)d_in[6];
    const float* b2  = (const float*)d_in[7];

    const int N = in_sizes[0] / 128;
    const int E = in_sizes[1] / 2;
    const int* src = ei;
    const int* dst = ei + E;
    const int NB = (N + NPB - 1) / NPB;             // 196 buckets for N=100000
    const int NSC = (E + CHUNK - 1) / CHUNK;        // 196 scatter blocks

    size_t off = 0;
    auto take = [&](size_t nbytes) -> void* {
        void* ptr = (void*)((char*)d_ws + off);
        off += (nbytes + 255) & ~(size_t)255;
        return ptr;
    };
    int*      bcount    = (int*)take((size_t)NB * 4);
    unsigned* bbuf      = (unsigned*)take((size_t)NB * BCAP * 4);   // 12.8 MB
    int*      row_start = (int*)take((size_t)N * 4);
    int*      degw      = (int*)take((size_t)N * 4);
    float*    inv_deg   = (float*)take((size_t)N * 4);
    int*      ssrc      = (int*)take((size_t)NB * BCAP * 4);        // 12.8 MB (bucket-strided)
    unsigned char* p8   = (unsigned char*)take((size_t)N * 128);    // reused as u8
    ushort*   q         = (ushort*)take((size_t)N * 128 * 2);       // reused as v
    ushort*   hb        = (ushort*)take((size_t)N * 128 * 2);
    ushort*   Wf_l1     = (ushort*)take(128 * 128 * 2);
    ushort*   Wf_r1     = (ushort*)take(128 * 128 * 2);
    ushort*   Wf_l2     = (ushort*)take(64 * 128 * 2);
    ushort*   Wf_r2     = (ushort*)take(64 * 128 * 2);
    unsigned char* u8 = p8;   // p dead after agg_relu
    ushort*        v  = q;    // q dead after agg_relu
    (void)ws_size; (void)n_in; (void)out_size;

    hipMemsetAsync(bcount, 0, (size_t)NB * 4, stream);

    // K1: scatter || weight repack (independent)
    k1_scatter_cvtw<<<NSC + 192, 256, 0, stream>>>(src, dst, bcount, bbuf, E, NSC,
                                                   Wl1, Wr1, Wl2, Wr2,
                                                   Wf_l1, Wf_r1, Wf_l2, Wf_r2);

    // K2: build_csr (bucket-local row_start, no scan) || proj1 (independent)
    int P1 = (N + 63) / 64;
    k2_csr_proj1<<<NB + P1, 256, 0, stream>>>(bbuf, bcount, row_start, degw, inv_deg,
                                              ssrc, NB, N, x, Wf_l1, Wf_r1, b1, p8, q);

    // layer 1 aggregate
    agg_relu_kernel<<<(N + 3) / 4, 256, 0, stream>>>(p8, q, ssrc, row_start, degw, inv_deg, hb, N);

    // layer 2
    proj2_kernel<<<(N + 63) / 64, 256, 0, stream>>>(hb, Wf_l2, Wf_r2, b2, u8, v, N);
    agg_lsm_kernel<<<(N + 3) / 4, 256, 0, stream>>>(u8, v, ssrc, row_start, degw, inv_deg,
                                                    (float*)d_out, N);
}